// Round 5
// baseline (190.633 us; speedup 1.0000x reference)
//
#include <hip/hip_runtime.h>
#include <hip/hip_bf16.h>

typedef __attribute__((ext_vector_type(8))) short short8;       // 8 bf16 (MFMA operand)
typedef __attribute__((ext_vector_type(4))) float f32x4;        // MFMA accumulator
typedef unsigned short u16;
typedef unsigned int u32;
typedef __attribute__((ext_vector_type(8))) unsigned short u16x8;
typedef __attribute__((ext_vector_type(4))) unsigned short u16x4;

__device__ __forceinline__ u16 f2bf(float f) {
    u32 u = __builtin_bit_cast(u32, f);
    u += 0x7FFFu + ((u >> 16) & 1u);   // RNE
    return (u16)(u >> 16);
}
// single-instruction packed f32->bf16 (RNE), lo = a, hi = b
__device__ __forceinline__ u32 cvtpk(float a, float b) {
    u32 r;
    asm("v_cvt_pk_bf16_f32 %0, %1, %2" : "=v"(r) : "v"(a), "v"(b));
    return r;
}
// raw v_exp_f32: exact for our domain (args <= 0; deeply negative -> 0 is the
// desired masked value). Avoids ocml's denorm-fixup expansion (~6 VALU ops).
__device__ __forceinline__ float fexp2(float x) {
    float r;
    asm("v_exp_f32 %0, %1" : "=v"(r) : "v"(x));
    return r;
}

// XOR swizzle for [R]-row bf16 LDS tiles, row pitch 128B (K tile).
__device__ __forceinline__ int swz(int row, int col) {
    return (row * 128 + col * 2) ^ ((row & 7) << 4);
}
// row pitch 256B variant (V tile, 128 kv-cols).
__device__ __forceinline__ int swzV(int row, int col) {
    return (row * 256 + col * 2) ^ ((row & 7) << 4);
}

// async global->LDS, 16B per lane; LDS dest linear, any swizzle pre-applied on source.
__device__ __forceinline__ void gl16(const void* g, void* l) {
    __builtin_amdgcn_global_load_lds(
        (const __attribute__((address_space(1))) unsigned int*)g,
        (__attribute__((address_space(3))) unsigned int*)l, 16, 0, 0);
}

#define FENCE() asm volatile("" ::: "memory")
#define BARRIER() do { FENCE(); __builtin_amdgcn_s_barrier(); FENCE(); } while (0)

// ------------------------------------------------------------------ prep ----
// bid < 8192: query/value f32 -> bf16 (cvt). bid >= 8192: W transpose (4096
// blocks, z = (bid-8192)>>10). Merged so they share one dispatch instead of
// serializing on the stream.
__global__ __launch_bounds__(256)
void prep_kernel(const float* __restrict__ query, const float* __restrict__ value,
                 u16* __restrict__ qB, u16* __restrict__ vB,
                 const float* __restrict__ W0, const float* __restrict__ W1,
                 const float* __restrict__ W2, const float* __restrict__ W3,
                 u16* __restrict__ T0, u16* __restrict__ T1,
                 u16* __restrict__ T2, u16* __restrict__ T3)
{
    int bid = blockIdx.x;
    if (bid < 8192) {
        const float* src; u16* dst;
        if (bid < 4096) { src = query; dst = qB; }
        else            { src = value; dst = vB; bid -= 4096; }
        const int i = bid * 256 + threadIdx.x;          // 8 floats each
        const float4 a = ((const float4*)src)[2 * i];
        const float4 b = ((const float4*)src)[2 * i + 1];
        u16x8 h;
        h[0] = f2bf(a.x); h[1] = f2bf(a.y); h[2] = f2bf(a.z); h[3] = f2bf(a.w);
        h[4] = f2bf(b.x); h[5] = f2bf(b.y); h[6] = f2bf(b.z); h[7] = f2bf(b.w);
        ((u16x8*)dst)[i] = h;
        return;
    }
    // ---- wtrans: W [1024][1024] f32 (k-major) -> WT bf16, WT[n][k] = W[k][n]
    int b2 = bid - 8192;
    const int z = b2 >> 10; b2 &= 1023;
    const float* W; u16* T;
    switch (z) {
        case 0:  W = W0; T = T0; break;
        case 1:  W = W1; T = T1; break;
        case 2:  W = W2; T = T2; break;
        default: W = W3; T = T3; break;
    }
    __shared__ u16 tile[32][33];
    const int tid = threadIdx.x;
    const int n0 = (b2 & 31) * 32, k0 = (b2 >> 5) * 32;
    const int r = tid >> 3, c = (tid & 7) * 4;
    float4 v = *(const float4*)(W + (size_t)(k0 + r) * 1024 + n0 + c);
    tile[c + 0][r] = f2bf(v.x);
    tile[c + 1][r] = f2bf(v.y);
    tile[c + 2][r] = f2bf(v.z);
    tile[c + 3][r] = f2bf(v.w);
    __syncthreads();
    u16x4 h;
    h[0] = tile[r][c]; h[1] = tile[r][c + 1]; h[2] = tile[r][c + 2]; h[3] = tile[r][c + 3];
    *(u16x4*)(T + (size_t)(n0 + r) * 1024 + k0 + c) = h;
}

// ------------------------------------------------- pipelined GEMM core ------
// C tile = 128(M) x 256(N), BK=32, K=1024 (NK=32 k-tiles), 8 waves (2Mx4N),
// per-wave 64x64 (4x4 frags). 3-buffer LDS ring (24KB each: A 8KB + B 16KB)
// = 72KB -> 2 blocks/CU. Iter k: computes ktile k; stages ktile k+2.
// Counted vmcnt(3) steady-state -- never 0 mid-loop.
// LDS slot-XOR: slot s of row r holds global chunk (s ^ (r&3)); reader uses
// slot = lhi ^ (r&3). 16B chunks, row pitch 64B.
#define GNK 32

__device__ __forceinline__ void stage_a(const u16* __restrict__ A, unsigned char* bufA,
                                        int row0, int kt, int tid) {
    const int r = tid >> 2, s = tid & 3;
    gl16((const unsigned char*)A + (size_t)(row0 + r) * 2048 + kt * 64 + ((s ^ (r & 3)) << 4),
         bufA + tid * 16);
}
__device__ __forceinline__ void stage_b(const u16* __restrict__ BT, unsigned char* bufB,
                                        int col0, int kt, int hb, int tid) {
    const int r = hb * 128 + (tid >> 2), s = tid & 3;
    gl16((const unsigned char*)BT + (size_t)(col0 + r) * 2048 + kt * 64 + ((s ^ (r & 3)) << 4),
         bufB + hb * 8192 + tid * 16);
}

__device__ __forceinline__ void gemm_core(const u16* __restrict__ A, const u16* __restrict__ BT,
                                          int row0, int col0, unsigned char* smem,
                                          int tid, int wm, int wn, int l15, int lhi,
                                          f32x4 acc[4][4])
{
    const int slot = (lhi ^ (l15 & 3)) << 4;        // byte offset of reader chunk
    // prologue: stage ktiles 0..1 (6 loads/thread)
    #pragma unroll
    for (int kt = 0; kt < 2; ++kt) {
        unsigned char* buf = smem + kt * 24576;
        stage_a(A, buf, row0, kt, tid);
        stage_b(BT, buf + 8192, col0, kt, 0, tid);
        stage_b(BT, buf + 8192, col0, kt, 1, tid);
    }
    asm volatile("s_waitcnt vmcnt(3)" ::: "memory");
    BARRIER();

    int cb = 0;                                     // ring slot of ktile k
    for (int k = 0; k < GNK; ++k) {
        unsigned char* bufA = smem + cb * 24576;
        unsigned char* bufB = bufA + 8192;
        const bool st = (k + 2 < GNK);
        int nb = cb + 2; if (nb >= 3) nb -= 3;      // ring slot of ktile k+2
        unsigned char* nbuf = smem + nb * 24576;
        cb = (cb == 2) ? 0 : cb + 1;

        // ---- phase 0: read A frags + B frags n=0,1; stage A(k+2); MFMA n=0,1
        short8 a0, a1, a2, a3, b0, b1;
        a0 = *(const short8*)(bufA + (wm * 64 + 0 * 16 + l15) * 64 + slot);
        a1 = *(const short8*)(bufA + (wm * 64 + 1 * 16 + l15) * 64 + slot);
        a2 = *(const short8*)(bufA + (wm * 64 + 2 * 16 + l15) * 64 + slot);
        a3 = *(const short8*)(bufA + (wm * 64 + 3 * 16 + l15) * 64 + slot);
        b0 = *(const short8*)(bufB + (wn * 64 + 0 * 16 + l15) * 64 + slot);
        b1 = *(const short8*)(bufB + (wn * 64 + 1 * 16 + l15) * 64 + slot);
        if (st) stage_a(A, nbuf, row0, k + 2, tid);
        BARRIER();
        __builtin_amdgcn_s_setprio(1);
        acc[0][0] = __builtin_amdgcn_mfma_f32_16x16x32_bf16(a0, b0, acc[0][0], 0, 0, 0);
        acc[0][1] = __builtin_amdgcn_mfma_f32_16x16x32_bf16(a0, b1, acc[0][1], 0, 0, 0);
        acc[1][0] = __builtin_amdgcn_mfma_f32_16x16x32_bf16(a1, b0, acc[1][0], 0, 0, 0);
        acc[1][1] = __builtin_amdgcn_mfma_f32_16x16x32_bf16(a1, b1, acc[1][1], 0, 0, 0);
        acc[2][0] = __builtin_amdgcn_mfma_f32_16x16x32_bf16(a2, b0, acc[2][0], 0, 0, 0);
        acc[2][1] = __builtin_amdgcn_mfma_f32_16x16x32_bf16(a2, b1, acc[2][1], 0, 0, 0);
        acc[3][0] = __builtin_amdgcn_mfma_f32_16x16x32_bf16(a3, b0, acc[3][0], 0, 0, 0);
        acc[3][1] = __builtin_amdgcn_mfma_f32_16x16x32_bf16(a3, b1, acc[3][1], 0, 0, 0);
        __builtin_amdgcn_s_setprio(0);
        BARRIER();

        // ---- phase 1: read B frags n=2,3; stage B(k+2); counted vmcnt; MFMA n=2,3
        short8 b2, b3;
        b2 = *(const short8*)(bufB + (wn * 64 + 2 * 16 + l15) * 64 + slot);
        b3 = *(const short8*)(bufB + (wn * 64 + 3 * 16 + l15) * 64 + slot);
        if (st) {
            stage_b(BT, nbuf + 8192, col0, k + 2, 0, tid);
            stage_b(BT, nbuf + 8192, col0, k + 2, 1, tid);
        }
        if (k < GNK - 2)       asm volatile("s_waitcnt vmcnt(3)" ::: "memory");
        else if (k == GNK - 2) asm volatile("s_waitcnt vmcnt(0)" ::: "memory");
        BARRIER();
        __builtin_amdgcn_s_setprio(1);
        acc[0][2] = __builtin_amdgcn_mfma_f32_16x16x32_bf16(a0, b2, acc[0][2], 0, 0, 0);
        acc[0][3] = __builtin_amdgcn_mfma_f32_16x16x32_bf16(a0, b3, acc[0][3], 0, 0, 0);
        acc[1][2] = __builtin_amdgcn_mfma_f32_16x16x32_bf16(a1, b2, acc[1][2], 0, 0, 0);
        acc[1][3] = __builtin_amdgcn_mfma_f32_16x16x32_bf16(a1, b3, acc[1][3], 0, 0, 0);
        acc[2][2] = __builtin_amdgcn_mfma_f32_16x16x32_bf16(a2, b2, acc[2][2], 0, 0, 0);
        acc[2][3] = __builtin_amdgcn_mfma_f32_16x16x32_bf16(a2, b3, acc[2][3], 0, 0, 0);
        acc[3][2] = __builtin_amdgcn_mfma_f32_16x16x32_bf16(a3, b2, acc[3][2], 0, 0, 0);
        acc[3][3] = __builtin_amdgcn_mfma_f32_16x16x32_bf16(a3, b3, acc[3][3], 0, 0, 0);
        __builtin_amdgcn_s_setprio(0);
        BARRIER();
    }
}

// ------------------------------------------------------------------ proj ----
// 768 blocks x 512 thr, XCD-chunked (chunk 96). t: z = t/256, tile = t%256,
// row0 = (tile>>2)*128, col0 = (tile&3)*256. 72KB LDS -> 2 blocks/CU.
// z=0: Q = (queryB@Wq+bq)*(log2e/8) -> [B,H,Tq,64]
// z=1: K =  valueB@Wk+bk            -> [B,H,Tv,64]
// z=2: V^T = (valueB@Wv+bv)^T       -> [B,H,64,Tv]
__global__ __launch_bounds__(512, 4)
void proj_kernel(const u16* __restrict__ queryB, const u16* __restrict__ valueB,
                 const u16* __restrict__ WqT, const u16* __restrict__ WkT,
                 const u16* __restrict__ WvT,
                 const float* __restrict__ bq, const float* __restrict__ bk,
                 const float* __restrict__ bv,
                 u16* __restrict__ Qb, u16* __restrict__ Kb, u16* __restrict__ Vt)
{
    __shared__ __align__(16) unsigned char smem[73728];
    const int t = (blockIdx.x & 7) * 96 + (blockIdx.x >> 3);
    const int z = t >> 8;
    const int tile = t & 255;
    const int row0 = (tile >> 2) * 128, col0 = (tile & 3) * 256;

    const u16* A    = (z == 0) ? queryB : valueB;
    const u16* BT   = (z == 0) ? WqT : (z == 1) ? WkT : WvT;
    const float* bias = (z == 0) ? bq : (z == 1) ? bk : bv;

    const int tid = threadIdx.x;
    const int lane = tid & 63, w = tid >> 6;
    const int wm = w >> 2, wn = w & 3;
    const int l15 = lane & 15, lhi = lane >> 4;

    f32x4 acc[4][4];
    const f32x4 fz = {0.f, 0.f, 0.f, 0.f};
    #pragma unroll
    for (int m = 0; m < 4; ++m)
        #pragma unroll
        for (int n = 0; n < 4; ++n) acc[m][n] = fz;

    gemm_core(A, BT, row0, col0, smem, tid, wm, wn, l15, lhi, acc);

    if (z < 2) {
        u16* out = (z == 0) ? Qb : Kb;
        const float scale = (z == 0) ? 0.18033688011112042f : 1.0f;  // log2e/8
        const int bb = row0 >> 11;
        #pragma unroll
        for (int n = 0; n < 4; ++n) {
            int col = col0 + wn * 64 + n * 16 + l15;
            int hh = col >> 6, d = col & 63;
            float bv2 = bias[col];
            #pragma unroll
            for (int m = 0; m < 4; ++m) {
                int rbase = row0 + wm * 64 + m * 16 + lhi * 4;
                #pragma unroll
                for (int rr = 0; rr < 4; ++rr) {
                    int trow = (rbase + rr) & 2047;
                    out[(((size_t)bb * 16 + hh) * 2048 + trow) * 64 + d] =
                        f2bf((acc[m][n][rr] + bv2) * scale);
                }
            }
        }
    } else {
        // transpose epilogue: vl[256 cols][132 rows] (67.5KB <= 72KB)
        __syncthreads();
        u16* vl = (u16*)smem;
        #pragma unroll
        for (int n = 0; n < 4; ++n) {
            int c = wn * 64 + n * 16 + l15;
            float bv2 = bias[col0 + c];
            #pragma unroll
            for (int m = 0; m < 4; ++m) {
                int rl = wm * 64 + m * 16 + lhi * 4;
                u16x4 h;
                #pragma unroll
                for (int rr = 0; rr < 4; ++rr) h[rr] = f2bf(acc[m][n][rr] + bv2);
                *(u16x4*)(vl + c * 132 + rl) = h;
            }
        }
        __syncthreads();
        const int bb = row0 >> 11, t0 = row0 & 2047;
        const int c = tid >> 1, hseg = tid & 1;
        const int col = col0 + c;
        const int hh = col >> 6, d = col & 63;
        size_t gb = (((size_t)bb * 16 + hh) * 64 + d) * 2048 + t0 + hseg * 64;
        #pragma unroll
        for (int j = 0; j < 8; ++j) {
            u16x8 v = *(const u16x8*)(vl + c * 132 + hseg * 64 + j * 8);
            *(u16x8*)(Vt + gb + j * 8) = v;
        }
    }
}

// ----------------------------------------------------------------- fgemm ----
// 256 blocks x 512 thr (1 full round). out f32 = Ctx(bf16)@Wf + bf.
__global__ __launch_bounds__(512, 4)
void fgemm_kernel(const u16* __restrict__ Ctx, const u16* __restrict__ WfT,
                  const float* __restrict__ bias, float* __restrict__ out)
{
    __shared__ __align__(16) unsigned char smem[73728];
    const int t = (blockIdx.x & 7) * 32 + (blockIdx.x >> 3);
    const int row0 = (t >> 2) * 128, col0 = (t & 3) * 256;

    const int tid = threadIdx.x;
    const int lane = tid & 63, w = tid >> 6;
    const int wm = w >> 2, wn = w & 3;
    const int l15 = lane & 15, lhi = lane >> 4;

    f32x4 acc[4][4];
    const f32x4 fz = {0.f, 0.f, 0.f, 0.f};
    #pragma unroll
    for (int m = 0; m < 4; ++m)
        #pragma unroll
        for (int n = 0; n < 4; ++n) acc[m][n] = fz;

    gemm_core(Ctx, WfT, row0, col0, smem, tid, wm, wn, l15, lhi, acc);

    #pragma unroll
    for (int n = 0; n < 4; ++n) {
        int col = col0 + wn * 64 + n * 16 + l15;
        float bv2 = bias[col];
        #pragma unroll
        for (int m = 0; m < 4; ++m) {
            int rbase = row0 + wm * 64 + m * 16 + lhi * 4;
            #pragma unroll
            for (int rr = 0; rr < 4; ++rr)
                out[(size_t)(rbase + rr) * 1024 + col] = acc[m][n][rr] + bv2;
        }
    }
}

// ------------------------------------------------------------------ attn ----
// Balanced flash attention: every block does IDENTICAL work.
// Grid 512 = (hh 16) x (qt 32 tiles of 64 q-rows). Each block chains ALL 4
// batches (b=0..3), so per-block work = sum_b ceil(len_b/128) -- constant
// regardless of the lens draw (fixes the R3/R4 drain tail: duration was set
// by nt_max blocks running on a half-empty machine; occupancy 50-54%).
// KVBLK=128 split across 2 wave-groups: waves 0-3 take kv [t*128, +64),
// waves 4-7 take [+64, +128) for the SAME 64 q-rows, each with private
// online-softmax state; one exact LDS merge per (b) item combines halves.
// LDS 64KB (K 2x16KB + V 2x16KB dbuf) -> 2 blocks/CU, 16 waves/CU steady.
// Merge scratch overlays buffers[1] (free after last-tile sync; next item's
// stage(0) only touches buffers[0]).
__global__ __launch_bounds__(512, 4)
void attn_kernel(const u16* __restrict__ Qb, const u16* __restrict__ Kb,
                 const u16* __restrict__ Vt, const int* __restrict__ lens,
                 u16* __restrict__ Ctx)
{
    __shared__ __align__(16) unsigned char sm[65536];
    // K buffers: sm + bi*16384, V buffers: sm + 32768 + bi*16384.
    // Merge overlay: mb1 over K-buf[1], mb2 over V-buf[1] (12 f32/lane each).
    float* mb1 = (float*)(sm + 16384);
    float* mb2 = (float*)(sm + 49152);

    const int tid = threadIdx.x;
    const int lane = tid & 63;
    const int w = tid >> 6;                 // 0..7
    const int g = w >> 2;                   // KV half 0/1
    const int wq = w & 3;                   // q-subtile (16 rows)
    const int l15 = lane & 15, lhi = lane >> 4;

    const int u = blockIdx.x;               // 512 blocks
    const int hh = ((u >> 3) & 1) * 8 + (u & 7);   // head pinned to XCD u&7
    const int qt = u >> 4;                  // 0..31, 64-row q tiles

    const int o0 = tid * 16;                // staging offset, 8KB span
    const int r0k = o0 >> 7;                // K row 0..63 (first call)
    const int sck = (o0 & 127) ^ ((r0k & 7) << 4);
    const int r0v = o0 >> 8;                // V row 0..31 (first call)
    const int scv = (o0 & 255) ^ ((r0v & 7) << 4);

    short8 onesv;
    #pragma unroll
    for (int i = 0; i < 8; ++i) onesv[i] = (short)0x3F80;

    const int srcA = l15 + (((2 * lhi) & 3) << 4);
    const int srcB = l15 + (((2 * lhi + 1) & 3) << 4);
    const bool hi = lhi >= 2;
    const f32x4 fz = {0.f, 0.f, 0.f, 0.f};

    for (int b = 0; b < 4; ++b) {
        const size_t head = (size_t)(b * 16 + hh);
        const unsigned char* Kp = (const unsigned char*)Kb + head * 262144 + r0k * 128 + sck;
        const unsigned char* Vp = (const unsigned char*)Vt + head * 262144 + (size_t)r0v * 4096 + scv;
        const unsigned char* Qbase = (const unsigned char*)Qb + head * 262144 + (size_t)qt * 8192;

        const int lens_b = lens[b];
        const bool uniform = (lens_b == 0);     // softmax of all-(-LARGE) -> uniform
        const int len = uniform ? 2048 : lens_b;
        const int nt = (len + 127) >> 7;
        const bool tail = (!uniform) && ((len & 127) != 0);

        auto stage = [&](int t, int bi) {
            unsigned char* kd = sm + bi * 16384;
            unsigned char* vd = sm + 32768 + bi * 16384;
            gl16(Kp + (size_t)t * 16384,        kd + o0);
            gl16(Kp + (size_t)t * 16384 + 8192, kd + o0 + 8192);
            gl16(Vp + (size_t)t * 256,          vd + o0);
            gl16(Vp + (size_t)t * 256 + 131072, vd + o0 + 8192);
        };
        stage(0, 0);        // touches only buffers[0]; prev item's merge used buffers[1]

        short8 qa[2];
        #pragma unroll
        for (int ks = 0; ks < 2; ++ks)
            qa[ks] = *(const short8*)(Qbase + (wq * 16 + l15) * 128 + ks * 64 + lhi * 16);

        float m = -1e30f;
        f32x4 cs = fz;                          // denominator accumulator
        f32x4 cT[4];
        #pragma unroll
        for (int nf = 0; nf < 4; ++nf) cT[nf] = fz;

        __syncthreads();    // stage(0) drained; prev merge reads complete

        for (int t = 0; t < nt; ++t) {
            const int cur = t & 1;
            if (t + 1 < nt) stage(t + 1, cur ^ 1);
            const unsigned char* kcur = sm + cur * 16384;
            const unsigned char* vcur = sm + 32768 + cur * 16384;

            f32x4 s[4];
            #pragma unroll
            for (int jf = 0; jf < 4; ++jf) s[jf] = fz;
            if (!uniform) {
                __builtin_amdgcn_s_setprio(1);
                #pragma unroll
                for (int ks = 0; ks < 2; ++ks)
                    #pragma unroll
                    for (int jf = 0; jf < 4; ++jf) {
                        short8 kb = *(const short8*)(kcur + swz(g * 64 + jf * 16 + l15, ks * 32 + lhi * 8));
                        s[jf] = __builtin_amdgcn_mfma_f32_16x16x32_bf16(kb, qa[ks], s[jf], 0, 0, 0);
                    }
                __builtin_amdgcn_s_setprio(0);
                if (tail && t == nt - 1) {
                    const int kvb = t * 128 + g * 64 + lhi * 4;
                    #pragma unroll
                    for (int jf = 0; jf < 4; ++jf)
                        #pragma unroll
                        for (int r = 0; r < 4; ++r)
                            if (kvb + jf * 16 + r >= len) s[jf][r] = -1e30f;
                }
            }
            f32x4 m4;
            #pragma unroll
            for (int r = 0; r < 4; ++r)
                m4[r] = fmaxf(fmaxf(s[0][r], s[1][r]), fmaxf(s[2][r], s[3][r]));
            float tmax = fmaxf(fmaxf(m4[0], m4[1]), fmaxf(m4[2], m4[3]));
            tmax = fmaxf(tmax, __shfl_xor(tmax, 16));
            tmax = fmaxf(tmax, __shfl_xor(tmax, 32));
            // defer-max (T13): only rescale when tile max exceeds m by >8.
            if (__any(tmax > m + 8.f)) {
                const float mnew = fmaxf(m, tmax);
                const float sc = fexp2(m - mnew);
                #pragma unroll
                for (int r = 0; r < 4; ++r) cs[r] *= sc;
                #pragma unroll
                for (int nf = 0; nf < 4; ++nf)
                    #pragma unroll
                    for (int r = 0; r < 4; ++r) cT[nf][r] *= sc;
                m = mnew;
            }
            #pragma unroll
            for (int jf = 0; jf < 4; ++jf)
                #pragma unroll
                for (int r = 0; r < 4; ++r)
                    s[jf][r] = fexp2(s[jf][r] - m);
            // pack P -> bf16 pairs (v_cvt_pk_bf16_f32)
            u32 pk[4][2];
            #pragma unroll
            for (int jf = 0; jf < 4; ++jf) {
                pk[jf][0] = cvtpk(s[jf][0], s[jf][1]);
                pk[jf][1] = cvtpk(s[jf][2], s[jf][3]);
            }
            short8 pb[2];
            #pragma unroll
            for (int ks = 0; ks < 2; ++ks) {
                u32 a0, a1, a2, a3;
                { u32 x0 = (u32)__shfl((int)pk[2 * ks][0], srcA); u32 x1 = (u32)__shfl((int)pk[2 * ks + 1][0], srcA); a0 = hi ? x1 : x0; }
                { u32 x0 = (u32)__shfl((int)pk[2 * ks][1], srcA); u32 x1 = (u32)__shfl((int)pk[2 * ks + 1][1], srcA); a1 = hi ? x1 : x0; }
                { u32 x0 = (u32)__shfl((int)pk[2 * ks][0], srcB); u32 x1 = (u32)__shfl((int)pk[2 * ks + 1][0], srcB); a2 = hi ? x1 : x0; }
                { u32 x0 = (u32)__shfl((int)pk[2 * ks][1], srcB); u32 x1 = (u32)__shfl((int)pk[2 * ks + 1][1], srcB); a3 = hi ? x1 : x0; }
                typedef __attribute__((ext_vector_type(4))) unsigned int u32x4_t;
                u32x4_t av = {a0, a1, a2, a3};
                pb[ks] = __builtin_bit_cast(short8, av);
            }
            __builtin_amdgcn_s_setprio(1);
            #pragma unroll
            for (int ks = 0; ks < 2; ++ks) {
                cs = __builtin_amdgcn_mfma_f32_16x16x32_bf16(onesv, pb[ks], cs, 0, 0, 0);
                #pragma unroll
                for (int nf = 0; nf < 4; ++nf) {
                    short8 vb = *(const short8*)(vcur + swzV(nf * 16 + l15, g * 64 + ks * 32 + lhi * 8));
                    cT[nf] = __builtin_amdgcn_mfma_f32_16x16x32_bf16(vb, pb[ks], cT[nf], 0, 0, 0);
                }
            }
            __builtin_amdgcn_s_setprio(0);
            __syncthreads();
        }

        // ---- merge the two KV halves (exact flash merge), group 1 -> group 0
        const int ix = (wq * 64 + lane) * 12;
        if (g == 1) {
            *(f32x4*)(mb1 + ix)     = cT[0];
            *(f32x4*)(mb1 + ix + 4) = cT[1];
            *(f32x4*)(mb2 + ix)     = cT[2];
            *(f32x4*)(mb2 + ix + 4) = cT[3];
            mb1[ix + 8] = m;
            mb1[ix + 9] = cs[0];
        }
        __syncthreads();
        if (g == 0) {
            f32x4 cB[4];
            cB[0] = *(const f32x4*)(mb1 + ix);
            cB[1] = *(const f32x4*)(mb1 + ix + 4);
            cB[2] = *(const f32x4*)(mb2 + ix);
            cB[3] = *(const f32x4*)(mb2 + ix + 4);
            const float mB = mb1[ix + 8], csB = mb1[ix + 9];
            const float M  = fmaxf(m, mB);
            const float sA = fexp2(m - M), sB = fexp2(mB - M);
            const float inv = 1.0f / (cs[0] * sA + csB * sB);
            const int trow = qt * 64 + wq * 16 + l15;
            u16* op = Ctx + ((size_t)b * 2048 + trow) * 1024 + hh * 64 + lhi * 4;
            #pragma unroll
            for (int nf = 0; nf < 4; ++nf) {
                u16x4 h;
                #pragma unroll
                for (int r = 0; r < 4; ++r)
                    h[r] = f2bf((cT[nf][r] * sA + cB[nf][r] * sB) * inv);
                *(u16x4*)(op + nf * 16) = h;
            }
        }
        // no trailing sync: next item's stage(0) touches only buffers[0];
        // its post-init __syncthreads orders everything before stage(1,1)
        // overwrites the merge region (buffers[1]).
    }
}

// ---------------------------------------------------------------- launch ----
extern "C" void kernel_launch(void* const* d_in, const int* in_sizes, int n_in,
                              void* d_out, int out_size, void* d_ws, size_t ws_size,
                              hipStream_t stream)
{
    (void)in_sizes; (void)n_in; (void)out_size; (void)ws_size;
    const float* query = (const float*)d_in[0];
    const float* value = (const float*)d_in[1];
    const int*   lens  = (const int*)d_in[2];
    const float* Wq = (const float*)d_in[3];
    const float* bq = (const float*)d_in[4];
    const float* Wk = (const float*)d_in[5];
    const float* bk = (const float*)d_in[6];
    const float* Wv = (const float*)d_in[7];
    const float* bv = (const float*)d_in[8];
    const float* Wf = (const float*)d_in[9];
    const float* bfp = (const float*)d_in[10];

    unsigned char* ws = (unsigned char*)d_ws;
    const size_t MB = (size_t)1 << 20;
    u16* WqT = (u16*)(ws + 0 * MB);
    u16* WkT = (u16*)(ws + 2 * MB);
    u16* WvT = (u16*)(ws + 4 * MB);
    u16* WfT = (u16*)(ws + 6 * MB);
    u16* Qb  = (u16*)(ws + 8 * MB);    // [4,16,2048,64] bf16 (pre-scaled by log2e/8)
    u16* Kb  = (u16*)(ws + 24 * MB);   // [4,16,2048,64]
    u16* Vt  = (u16*)(ws + 40 * MB);   // [4,16,64,2048]
    u16* Ctx = (u16*)(ws + 56 * MB);   // [4,2048,1024]

    // d_out (32MB f32) doubles as bf16 scratch for query/value until fgemm runs
    u16* queryB = (u16*)d_out;                 // 16MB
    u16* valueB = queryB + (size_t)8192 * 1024; // 16MB

    prep_kernel<<<dim3(12288), dim3(256), 0, stream>>>(query, value, queryB, valueB,
                                                       Wq, Wk, Wv, Wf, WqT, WkT, WvT, WfT);

    proj_kernel<<<dim3(768), dim3(512), 0, stream>>>(queryB, valueB, WqT, WkT, WvT,
                                                     bq, bk, bv, Qb, Kb, Vt);

    attn_kernel<<<dim3(512), dim3(512), 0, stream>>>(Qb, Kb, Vt, lens, Ctx);

    fgemm_kernel<<<dim3(256), dim3(512), 0, stream>>>(Ctx, WfT, bfp, (float*)d_out);
}

// Round 7
// 173.275 us; speedup vs baseline: 1.1002x; 1.1002x over previous
//
#include <hip/hip_runtime.h>
#include <hip/hip_bf16.h>

typedef __attribute__((ext_vector_type(8))) short short8;       // 8 bf16 (MFMA operand)
typedef __attribute__((ext_vector_type(4))) short short4b;      // 4 bf16 (16x16x16 operand)
typedef __attribute__((ext_vector_type(4))) float f32x4;        // MFMA accumulator
typedef unsigned short u16;
typedef unsigned int u32;
typedef __attribute__((ext_vector_type(2))) unsigned int u32x2;
typedef __attribute__((ext_vector_type(8))) unsigned short u16x8;
typedef __attribute__((ext_vector_type(4))) unsigned short u16x4;

__device__ __forceinline__ u16 f2bf(float f) {
    u32 u = __builtin_bit_cast(u32, f);
    u += 0x7FFFu + ((u >> 16) & 1u);   // RNE
    return (u16)(u >> 16);
}
// single-instruction packed f32->bf16 (RNE), lo = a, hi = b
__device__ __forceinline__ u32 cvtpk(float a, float b) {
    u32 r;
    asm("v_cvt_pk_bf16_f32 %0, %1, %2" : "=v"(r) : "v"(a), "v"(b));
    return r;
}
// raw v_exp_f32: exact for our domain (args <= 0; deeply negative -> 0 is the
// desired masked value). Avoids ocml's denorm-fixup expansion (~6 VALU ops).
__device__ __forceinline__ float fexp2(float x) {
    float r;
    asm("v_exp_f32 %0, %1" : "=v"(r) : "v"(x));
    return r;
}
// K=16 bf16 MFMA. R6 lesson: inline-asm MFMA gets NO compiler hazard
// mitigation -- cvtpk(VALU) -> mfma(SrcB) back-to-back read garbage (NaN).
// Prefer the builtin (compiler inserts wait states); asm fallback carries an
// embedded s_nop 1 (>=2 wait states after any preceding VALU write).
#if defined(__has_builtin)
#if __has_builtin(__builtin_amdgcn_mfma_f32_16x16x16_bf16)
#define MFMA16(a, b, c) __builtin_amdgcn_mfma_f32_16x16x16_bf16((a), (b), (c), 0, 0, 0)
#elif __has_builtin(__builtin_amdgcn_mfma_f32_16x16x16bf16_1k)
#define MFMA16(a, b, c) __builtin_amdgcn_mfma_f32_16x16x16bf16_1k((a), (b), (c), 0, 0, 0)
#endif
#endif
#ifndef MFMA16
__device__ __forceinline__ f32x4 mfma16_asm(short4b a, short4b b, f32x4 c) {
    asm volatile("s_nop 1\n\tv_mfma_f32_16x16x16_bf16 %0, %1, %2, %0"
                 : "+v"(c) : "v"(a), "v"(b));
    return c;
}
#define MFMA16(a, b, c) mfma16_asm((a), (b), (c))
#endif

// XOR swizzle for [R][64]-bf16 LDS tiles (row pitch 128B) -- used by attn only.
__device__ __forceinline__ int swz(int row, int col) {
    return (row * 128 + col * 2) ^ ((row & 7) << 4);
}

// async global->LDS, 16B per lane; LDS dest linear, any swizzle pre-applied on source.
__device__ __forceinline__ void gl16(const void* g, void* l) {
    __builtin_amdgcn_global_load_lds(
        (const __attribute__((address_space(1))) unsigned int*)g,
        (__attribute__((address_space(3))) unsigned int*)l, 16, 0, 0);
}

#define FENCE() asm volatile("" ::: "memory")
#define BARRIER() do { FENCE(); __builtin_amdgcn_s_barrier(); FENCE(); } while (0)

// ------------------------------------------------------------------ prep ----
// bid < 8192: query/value f32 -> bf16 (cvt). bid >= 8192: W transpose (4096
// blocks, z = (bid-8192)>>10). Merged so they share one dispatch instead of
// serializing on the stream.
__global__ __launch_bounds__(256)
void prep_kernel(const float* __restrict__ query, const float* __restrict__ value,
                 u16* __restrict__ qB, u16* __restrict__ vB,
                 const float* __restrict__ W0, const float* __restrict__ W1,
                 const float* __restrict__ W2, const float* __restrict__ W3,
                 u16* __restrict__ T0, u16* __restrict__ T1,
                 u16* __restrict__ T2, u16* __restrict__ T3)
{
    int bid = blockIdx.x;
    if (bid < 8192) {
        const float* src; u16* dst;
        if (bid < 4096) { src = query; dst = qB; }
        else            { src = value; dst = vB; bid -= 4096; }
        const int i = bid * 256 + threadIdx.x;          // 8 floats each
        const float4 a = ((const float4*)src)[2 * i];
        const float4 b = ((const float4*)src)[2 * i + 1];
        u16x8 h;
        h[0] = f2bf(a.x); h[1] = f2bf(a.y); h[2] = f2bf(a.z); h[3] = f2bf(a.w);
        h[4] = f2bf(b.x); h[5] = f2bf(b.y); h[6] = f2bf(b.z); h[7] = f2bf(b.w);
        ((u16x8*)dst)[i] = h;
        return;
    }
    // ---- wtrans: W [1024][1024] f32 (k-major) -> WT bf16, WT[n][k] = W[k][n]
    int b2 = bid - 8192;
    const int z = b2 >> 10; b2 &= 1023;
    const float* W; u16* T;
    switch (z) {
        case 0:  W = W0; T = T0; break;
        case 1:  W = W1; T = T1; break;
        case 2:  W = W2; T = T2; break;
        default: W = W3; T = T3; break;
    }
    __shared__ u16 tile[32][33];
    const int tid = threadIdx.x;
    const int n0 = (b2 & 31) * 32, k0 = (b2 >> 5) * 32;
    const int r = tid >> 3, c = (tid & 7) * 4;
    float4 v = *(const float4*)(W + (size_t)(k0 + r) * 1024 + n0 + c);
    tile[c + 0][r] = f2bf(v.x);
    tile[c + 1][r] = f2bf(v.y);
    tile[c + 2][r] = f2bf(v.z);
    tile[c + 3][r] = f2bf(v.w);
    __syncthreads();
    u16x4 h;
    h[0] = tile[r][c]; h[1] = tile[r][c + 1]; h[2] = tile[r][c + 2]; h[3] = tile[r][c + 3];
    *(u16x4*)(T + (size_t)(n0 + r) * 1024 + k0 + c) = h;
}

// ------------------------------------------------- pipelined GEMM core ------
// C tile = 128(M) x 256(N), BK=32, K=1024 (NK=32 k-tiles), 8 waves (2Mx4N),
// per-wave 64x64 (4x4 frags). 3-buffer LDS ring (24KB each: A 8KB + B 16KB)
// = 72KB -> 2 blocks/CU (VGPR=88 also caps at 16 waves/CU). Iter k: computes
// ktile k; stages ktile k+2. Counted vmcnt(3) steady-state -- never 0 mid-loop.
// LDS slot-XOR: slot s of row r holds global chunk (s ^ (r&3)); reader uses
// slot = lhi ^ (r&3). 16B chunks, row pitch 64B.
#define GNK 32

__device__ __forceinline__ void stage_a(const u16* __restrict__ A, unsigned char* bufA,
                                        int row0, int kt, int tid) {
    const int r = tid >> 2, s = tid & 3;
    gl16((const unsigned char*)A + (size_t)(row0 + r) * 2048 + kt * 64 + ((s ^ (r & 3)) << 4),
         bufA + tid * 16);
}
__device__ __forceinline__ void stage_b(const u16* __restrict__ BT, unsigned char* bufB,
                                        int col0, int kt, int hb, int tid) {
    const int r = hb * 128 + (tid >> 2), s = tid & 3;
    gl16((const unsigned char*)BT + (size_t)(col0 + r) * 2048 + kt * 64 + ((s ^ (r & 3)) << 4),
         bufB + hb * 8192 + tid * 16);
}

__device__ __forceinline__ void gemm_core(const u16* __restrict__ A, const u16* __restrict__ BT,
                                          int row0, int col0, unsigned char* smem,
                                          int tid, int wm, int wn, int l15, int lhi,
                                          f32x4 acc[4][4])
{
    const int slot = (lhi ^ (l15 & 3)) << 4;        // byte offset of reader chunk
    // prologue: stage ktiles 0..1 (6 loads/thread)
    #pragma unroll
    for (int kt = 0; kt < 2; ++kt) {
        unsigned char* buf = smem + kt * 24576;
        stage_a(A, buf, row0, kt, tid);
        stage_b(BT, buf + 8192, col0, kt, 0, tid);
        stage_b(BT, buf + 8192, col0, kt, 1, tid);
    }
    asm volatile("s_waitcnt vmcnt(3)" ::: "memory");
    BARRIER();

    int cb = 0;                                     // ring slot of ktile k
    for (int k = 0; k < GNK; ++k) {
        unsigned char* bufA = smem + cb * 24576;
        unsigned char* bufB = bufA + 8192;
        const bool st = (k + 2 < GNK);
        int nb = cb + 2; if (nb >= 3) nb -= 3;      // ring slot of ktile k+2
        unsigned char* nbuf = smem + nb * 24576;
        cb = (cb == 2) ? 0 : cb + 1;

        // ---- phase 0: read A frags + B frags n=0,1; stage A(k+2); MFMA n=0,1
        short8 a0, a1, a2, a3, b0, b1;
        a0 = *(const short8*)(bufA + (wm * 64 + 0 * 16 + l15) * 64 + slot);
        a1 = *(const short8*)(bufA + (wm * 64 + 1 * 16 + l15) * 64 + slot);
        a2 = *(const short8*)(bufA + (wm * 64 + 2 * 16 + l15) * 64 + slot);
        a3 = *(const short8*)(bufA + (wm * 64 + 3 * 16 + l15) * 64 + slot);
        b0 = *(const short8*)(bufB + (wn * 64 + 0 * 16 + l15) * 64 + slot);
        b1 = *(const short8*)(bufB + (wn * 64 + 1 * 16 + l15) * 64 + slot);
        if (st) stage_a(A, nbuf, row0, k + 2, tid);
        BARRIER();
        __builtin_amdgcn_s_setprio(1);
        acc[0][0] = __builtin_amdgcn_mfma_f32_16x16x32_bf16(a0, b0, acc[0][0], 0, 0, 0);
        acc[0][1] = __builtin_amdgcn_mfma_f32_16x16x32_bf16(a0, b1, acc[0][1], 0, 0, 0);
        acc[1][0] = __builtin_amdgcn_mfma_f32_16x16x32_bf16(a1, b0, acc[1][0], 0, 0, 0);
        acc[1][1] = __builtin_amdgcn_mfma_f32_16x16x32_bf16(a1, b1, acc[1][1], 0, 0, 0);
        acc[2][0] = __builtin_amdgcn_mfma_f32_16x16x32_bf16(a2, b0, acc[2][0], 0, 0, 0);
        acc[2][1] = __builtin_amdgcn_mfma_f32_16x16x32_bf16(a2, b1, acc[2][1], 0, 0, 0);
        acc[3][0] = __builtin_amdgcn_mfma_f32_16x16x32_bf16(a3, b0, acc[3][0], 0, 0, 0);
        acc[3][1] = __builtin_amdgcn_mfma_f32_16x16x32_bf16(a3, b1, acc[3][1], 0, 0, 0);
        __builtin_amdgcn_s_setprio(0);
        BARRIER();

        // ---- phase 1: read B frags n=2,3; stage B(k+2); counted vmcnt; MFMA n=2,3
        short8 b2, b3;
        b2 = *(const short8*)(bufB + (wn * 64 + 2 * 16 + l15) * 64 + slot);
        b3 = *(const short8*)(bufB + (wn * 64 + 3 * 16 + l15) * 64 + slot);
        if (st) {
            stage_b(BT, nbuf + 8192, col0, k + 2, 0, tid);
            stage_b(BT, nbuf + 8192, col0, k + 2, 1, tid);
        }
        if (k < GNK - 2)       asm volatile("s_waitcnt vmcnt(3)" ::: "memory");
        else if (k == GNK - 2) asm volatile("s_waitcnt vmcnt(0)" ::: "memory");
        BARRIER();
        __builtin_amdgcn_s_setprio(1);
        acc[0][2] = __builtin_amdgcn_mfma_f32_16x16x32_bf16(a0, b2, acc[0][2], 0, 0, 0);
        acc[0][3] = __builtin_amdgcn_mfma_f32_16x16x32_bf16(a0, b3, acc[0][3], 0, 0, 0);
        acc[1][2] = __builtin_amdgcn_mfma_f32_16x16x32_bf16(a1, b2, acc[1][2], 0, 0, 0);
        acc[1][3] = __builtin_amdgcn_mfma_f32_16x16x32_bf16(a1, b3, acc[1][3], 0, 0, 0);
        acc[2][2] = __builtin_amdgcn_mfma_f32_16x16x32_bf16(a2, b2, acc[2][2], 0, 0, 0);
        acc[2][3] = __builtin_amdgcn_mfma_f32_16x16x32_bf16(a2, b3, acc[2][3], 0, 0, 0);
        acc[3][2] = __builtin_amdgcn_mfma_f32_16x16x32_bf16(a3, b2, acc[3][2], 0, 0, 0);
        acc[3][3] = __builtin_amdgcn_mfma_f32_16x16x32_bf16(a3, b3, acc[3][3], 0, 0, 0);
        __builtin_amdgcn_s_setprio(0);
        BARRIER();
    }
}

// ------------------------------------------------------------------ proj ----
// 768 blocks x 512 thr, XCD-chunked (chunk 96). t: z = t/256, tile = t%256,
// row0 = (tile>>2)*128, col0 = (tile&3)*256. 72KB LDS -> 2 blocks/CU.
// z=0: Q = (queryB@Wq+bq)*(log2e/8) -> [B,H,Tq,64]
// z=1: K =  valueB@Wk+bk            -> [B,H,Tv,64]
// z=2: V^T = (valueB@Wv+bv)^T       -> [B,H,64,Tv]
__global__ __launch_bounds__(512, 4)
void proj_kernel(const u16* __restrict__ queryB, const u16* __restrict__ valueB,
                 const u16* __restrict__ WqT, const u16* __restrict__ WkT,
                 const u16* __restrict__ WvT,
                 const float* __restrict__ bq, const float* __restrict__ bk,
                 const float* __restrict__ bv,
                 u16* __restrict__ Qb, u16* __restrict__ Kb, u16* __restrict__ Vt)
{
    __shared__ __align__(16) unsigned char smem[73728];
    const int t = (blockIdx.x & 7) * 96 + (blockIdx.x >> 3);
    const int z = t >> 8;
    const int tile = t & 255;
    const int row0 = (tile >> 2) * 128, col0 = (tile & 3) * 256;

    const u16* A    = (z == 0) ? queryB : valueB;
    const u16* BT   = (z == 0) ? WqT : (z == 1) ? WkT : WvT;
    const float* bias = (z == 0) ? bq : (z == 1) ? bk : bv;

    const int tid = threadIdx.x;
    const int lane = tid & 63, w = tid >> 6;
    const int wm = w >> 2, wn = w & 3;
    const int l15 = lane & 15, lhi = lane >> 4;

    f32x4 acc[4][4];
    const f32x4 fz = {0.f, 0.f, 0.f, 0.f};
    #pragma unroll
    for (int m = 0; m < 4; ++m)
        #pragma unroll
        for (int n = 0; n < 4; ++n) acc[m][n] = fz;

    gemm_core(A, BT, row0, col0, smem, tid, wm, wn, l15, lhi, acc);

    if (z < 2) {
        u16* out = (z == 0) ? Qb : Kb;
        const float scale = (z == 0) ? 0.18033688011112042f : 1.0f;  // log2e/8
        const int bb = row0 >> 11;
        #pragma unroll
        for (int n = 0; n < 4; ++n) {
            int col = col0 + wn * 64 + n * 16 + l15;
            int hh = col >> 6, d = col & 63;
            float bv2 = bias[col];
            #pragma unroll
            for (int m = 0; m < 4; ++m) {
                int rbase = row0 + wm * 64 + m * 16 + lhi * 4;
                #pragma unroll
                for (int rr = 0; rr < 4; ++rr) {
                    int trow = (rbase + rr) & 2047;
                    out[(((size_t)bb * 16 + hh) * 2048 + trow) * 64 + d] =
                        f2bf((acc[m][n][rr] + bv2) * scale);
                }
            }
        }
    } else {
        // transpose epilogue: vl[256 cols][132 rows] (67.5KB <= 72KB)
        __syncthreads();
        u16* vl = (u16*)smem;
        #pragma unroll
        for (int n = 0; n < 4; ++n) {
            int c = wn * 64 + n * 16 + l15;
            float bv2 = bias[col0 + c];
            #pragma unroll
            for (int m = 0; m < 4; ++m) {
                int rl = wm * 64 + m * 16 + lhi * 4;
                u16x4 h;
                #pragma unroll
                for (int rr = 0; rr < 4; ++rr) h[rr] = f2bf(acc[m][n][rr] + bv2);
                *(u16x4*)(vl + c * 132 + rl) = h;
            }
        }
        __syncthreads();
        const int bb = row0 >> 11, t0 = row0 & 2047;
        const int c = tid >> 1, hseg = tid & 1;
        const int col = col0 + c;
        const int hh = col >> 6, d = col & 63;
        size_t gb = (((size_t)bb * 16 + hh) * 64 + d) * 2048 + t0 + hseg * 64;
        #pragma unroll
        for (int j = 0; j < 8; ++j) {
            u16x8 v = *(const u16x8*)(vl + c * 132 + hseg * 64 + j * 8);
            *(u16x8*)(Vt + gb + j * 8) = v;
        }
    }
}

// ----------------------------------------------------------------- fgemm ----
// 256 blocks x 512 thr (1 full round). out f32 = Ctx(bf16)@Wf + bf.
__global__ __launch_bounds__(512, 4)
void fgemm_kernel(const u16* __restrict__ Ctx, const u16* __restrict__ WfT,
                  const float* __restrict__ bias, float* __restrict__ out)
{
    __shared__ __align__(16) unsigned char smem[73728];
    const int t = (blockIdx.x & 7) * 32 + (blockIdx.x >> 3);
    const int row0 = (t >> 2) * 128, col0 = (t & 3) * 256;

    const int tid = threadIdx.x;
    const int lane = tid & 63, w = tid >> 6;
    const int wm = w >> 2, wn = w & 3;
    const int l15 = lane & 15, lhi = lane >> 4;

    f32x4 acc[4][4];
    const f32x4 fz = {0.f, 0.f, 0.f, 0.f};
    #pragma unroll
    for (int m = 0; m < 4; ++m)
        #pragma unroll
        for (int n = 0; n < 4; ++n) acc[m][n] = fz;

    gemm_core(Ctx, WfT, row0, col0, smem, tid, wm, wn, l15, lhi, acc);

    #pragma unroll
    for (int n = 0; n < 4; ++n) {
        int col = col0 + wn * 64 + n * 16 + l15;
        float bv2 = bias[col];
        #pragma unroll
        for (int m = 0; m < 4; ++m) {
            int rbase = row0 + wm * 64 + m * 16 + lhi * 4;
            #pragma unroll
            for (int rr = 0; rr < 4; ++rr)
                out[(size_t)(rbase + rr) * 1024 + col] = acc[m][n][rr] + bv2;
        }
    }
}

// ------------------------------------------------------------------ attn ----
// Swapped-operand flash attention (R4 structure: 128 q-rows/block, 8 waves,
// KVBLK 64, K/V dbuf 32KB, 1024 blocks -> 4 blocks/CU, 32 waves/CU).
// Scores in log2 domain (log2e folded into Q projection) -> P = exp2(S - m).
// Shuffle-free PV: QK^T C-layout gives lane kv = jf*16 + lhi*4 + r; the
// B-operand of 16x16x16 bf16 MFMA needs exactly k = lhi*4 + j, so
// {cvtpk(s0,s1), cvtpk(s2,s3)} IS the P-fragment (no ds_bpermute/cndmask).
// PV = 16x MFMA16 (V-frags via 8B LDS reads); denominator = ones x P on the
// same pipe. Hazards handled by builtin (preferred) or embedded s_nop.
__global__ __launch_bounds__(512, 4)
void attn_kernel(const u16* __restrict__ Qb, const u16* __restrict__ Kb,
                 const u16* __restrict__ Vt, const int* __restrict__ lens,
                 u16* __restrict__ Ctx)
{
    __shared__ __align__(16) unsigned char ksm[2][8192];
    __shared__ __align__(16) unsigned char vsm[2][8192];

    const int tid = threadIdx.x;
    const int lane = tid & 63;
    const int w = tid >> 6;                 // 0..7
    const int l15 = lane & 15, lhi = lane >> 4;
    const int u = blockIdx.x;
    const int b = (u >> 8) & 3;             // same-CU blocks cover all batches
    const int v = u & 255;
    const int qt = (v >> 3) & 15;           // 16 q-tiles of 128 rows
    const int hh = ((v >> 7) & 1) * 8 + (v & 7);   // head pinned to XCD u&7
    const size_t head = (size_t)(b * 16 + hh);
    const unsigned char* Kbase = (const unsigned char*)Kb + head * (2048 * 128);
    const unsigned char* Vbase = (const unsigned char*)Vt + head * (2048 * 128);
    const unsigned char* Qbase = (const unsigned char*)Qb + head * (2048 * 128) + (size_t)qt * (128 * 128);

    const int o0 = w * 1024 + lane * 16;
    const int r0 = o0 >> 7;
    const int sc0 = (o0 & 127) ^ ((r0 & 7) << 4);

    // loop-invariant staging pointers (t advances by fixed byte strides)
    const unsigned char* kp = Kbase + (size_t)r0 * 128 + sc0;
    const unsigned char* vp = Vbase + (size_t)r0 * 4096 + sc0;

    const int lens_b = lens[b];
    const bool uniform = (lens_b == 0);     // softmax of all-(-LARGE) -> uniform
    const int len = uniform ? 2048 : lens_b;
    const int nt = (len + 63) >> 6;
    const bool tail = (!uniform) && ((len & 63) != 0);

    auto stage = [&](int t, int bi) {
        gl16(kp + (size_t)t * 8192, ksm[bi] + o0);
        gl16(vp + (size_t)t * 128, vsm[bi] + o0);
    };
    stage(0, 0);

    short8 qa[2];
    #pragma unroll
    for (int ks = 0; ks < 2; ++ks)
        qa[ks] = *(const short8*)(Qbase + (w * 16 + l15) * 128 + ks * 64 + lhi * 16);

    // constant bf16 1.0 A-operand for the denominator MFMA (K=16)
    short4b ones16;
    #pragma unroll
    for (int i = 0; i < 4; ++i) ones16[i] = (short)0x3F80;

    __syncthreads();

    float m = -1e30f;
    const f32x4 fz = {0.f, 0.f, 0.f, 0.f};
    f32x4 cs = fz;                          // row-sum accumulator (denominator)
    f32x4 cT[4];
    #pragma unroll
    for (int nf = 0; nf < 4; ++nf) cT[nf] = fz;

    for (int t = 0; t < nt; ++t) {
        const int cur = t & 1;
        if (t + 1 < nt) stage(t + 1, cur ^ 1);

        f32x4 s[4];
        #pragma unroll
        for (int jf = 0; jf < 4; ++jf) s[jf] = fz;
        if (!uniform) {
            __builtin_amdgcn_s_setprio(1);
            #pragma unroll
            for (int ks = 0; ks < 2; ++ks)
                #pragma unroll
                for (int jf = 0; jf < 4; ++jf) {
                    short8 kb = *(const short8*)(ksm[cur] + swz(jf * 16 + l15, ks * 32 + lhi * 8));
                    s[jf] = __builtin_amdgcn_mfma_f32_16x16x32_bf16(kb, qa[ks], s[jf], 0, 0, 0);
                }
            __builtin_amdgcn_s_setprio(0);
            if (tail && t == nt - 1) {
                const int kvb = t * 64 + lhi * 4;
                #pragma unroll
                for (int jf = 0; jf < 4; ++jf)
                    #pragma unroll
                    for (int r = 0; r < 4; ++r)
                        if (kvb + jf * 16 + r >= len) s[jf][r] = -1e30f;
            }
        }
        f32x4 m4;
        #pragma unroll
        for (int r = 0; r < 4; ++r)
            m4[r] = fmaxf(fmaxf(s[0][r], s[1][r]), fmaxf(s[2][r], s[3][r]));
        float tmax = fmaxf(fmaxf(m4[0], m4[1]), fmaxf(m4[2], m4[3]));
        tmax = fmaxf(tmax, __shfl_xor(tmax, 16));
        tmax = fmaxf(tmax, __shfl_xor(tmax, 32));
        // defer-max (T13): only rescale when the new tile max exceeds m by >8;
        // otherwise keep m (P bounded by 2^8, fine for f32 accum / bf16 P).
        if (__any(tmax > m + 8.f)) {
            const float mnew = fmaxf(m, tmax);
            const float sc = fexp2(m - mnew);
            #pragma unroll
            for (int r = 0; r < 4; ++r) cs[r] *= sc;
            #pragma unroll
            for (int nf = 0; nf < 4; ++nf)
                #pragma unroll
                for (int r = 0; r < 4; ++r) cT[nf][r] *= sc;
            m = mnew;
        }
        #pragma unroll
        for (int jf = 0; jf < 4; ++jf)
            #pragma unroll
            for (int r = 0; r < 4; ++r)
                s[jf][r] = fexp2(s[jf][r] - m);
        // P-fragments: lane holds kv = jf*16 + lhi*4 + r, which is EXACTLY the
        // 16x16x16 B-operand layout (k = lhi*4 + j). No cross-lane movement.
        short4b pf[4];
        #pragma unroll
        for (int jf = 0; jf < 4; ++jf) {
            u32x2 t2 = { cvtpk(s[jf][0], s[jf][1]), cvtpk(s[jf][2], s[jf][3]) };
            pf[jf] = __builtin_bit_cast(short4b, t2);
        }
        __builtin_amdgcn_s_setprio(1);
        #pragma unroll
        for (int jf = 0; jf < 4; ++jf) {
            // denominator on the matrix pipe: cs += ones^T . P  (all rows = colsum)
            cs = MFMA16(ones16, pf[jf], cs);
            #pragma unroll
            for (int nf = 0; nf < 4; ++nf) {
                short4b vb = *(const short4b*)(vsm[cur] + swz(nf * 16 + l15, jf * 16 + lhi * 4));
                cT[nf] = MFMA16(vb, pf[jf], cT[nf]);
            }
        }
        __builtin_amdgcn_s_setprio(0);
        __syncthreads();
    }

    // MFMA(VGPR-dest) -> VALU-read hazard guard for the asm-fallback path.
    asm volatile("s_nop 7");
    const float inv = 1.0f / cs[0];
    const int trow = qt * 128 + w * 16 + l15;
    u16* op = Ctx + ((size_t)b * 2048 + trow) * 1024 + hh * 64 + lhi * 4;
    #pragma unroll
    for (int nf = 0; nf < 4; ++nf) {
        u16x4 h;
        #pragma unroll
        for (int r = 0; r < 4; ++r) h[r] = f2bf(cT[nf][r] * inv);
        *(u16x4*)(op + nf * 16) = h;
    }
}

// ---------------------------------------------------------------- launch ----
extern "C" void kernel_launch(void* const* d_in, const int* in_sizes, int n_in,
                              void* d_out, int out_size, void* d_ws, size_t ws_size,
                              hipStream_t stream)
{
    (void)in_sizes; (void)n_in; (void)out_size; (void)ws_size;
    const float* query = (const float*)d_in[0];
    const float* value = (const float*)d_in[1];
    const int*   lens  = (const int*)d_in[2];
    const float* Wq = (const float*)d_in[3];
    const float* bq = (const float*)d_in[4];
    const float* Wk = (const float*)d_in[5];
    const float* bk = (const float*)d_in[6];
    const float* Wv = (const float*)d_in[7];
    const float* bv = (const float*)d_in[8];
    const float* Wf = (const float*)d_in[9];
    const float* bfp = (const float*)d_in[10];

    unsigned char* ws = (unsigned char*)d_ws;
    const size_t MB = (size_t)1 << 20;
    u16* WqT = (u16*)(ws + 0 * MB);
    u16* WkT = (u16*)(ws + 2 * MB);
    u16* WvT = (u16*)(ws + 4 * MB);
    u16* WfT = (u16*)(ws + 6 * MB);
    u16* Qb  = (u16*)(ws + 8 * MB);    // [4,16,2048,64] bf16 (pre-scaled by log2e/8)
    u16* Kb  = (u16*)(ws + 24 * MB);   // [4,16,2048,64]
    u16* Vt  = (u16*)(ws + 40 * MB);   // [4,16,64,2048]
    u16* Ctx = (u16*)(ws + 56 * MB);   // [4,2048,1024]

    // d_out (32MB f32) doubles as bf16 scratch for query/value until fgemm runs
    u16* queryB = (u16*)d_out;                 // 16MB
    u16* valueB = queryB + (size_t)8192 * 1024; // 16MB

    prep_kernel<<<dim3(12288), dim3(256), 0, stream>>>(query, value, queryB, valueB,
                                                       Wq, Wk, Wv, Wf, WqT, WkT, WvT, WfT);

    proj_kernel<<<dim3(768), dim3(512), 0, stream>>>(queryB, valueB, WqT, WkT, WvT,
                                                     bq, bk, bv, Qb, Kb, Vt);

    attn_kernel<<<dim3(1024), dim3(512), 0, stream>>>(Qb, Kb, Vt, lens, Ctx);

    fgemm_kernel<<<dim3(256), dim3(512), 0, stream>>>(Ctx, WfT, bfp, (float*)d_out);
}